// Round 1
// baseline (600.608 us; speedup 1.0000x reference)
//
#include <hip/hip_runtime.h>
#include <hip/hip_bf16.h>
#include <stdint.h>

#define NN 100000
#define NE 3200000
#define EF 24
#define KF 536
#define KPAD 544
#define BM 64

typedef __attribute__((ext_vector_type(8))) short bf16x8;
typedef __attribute__((ext_vector_type(4))) float f32x4;

__device__ __forceinline__ unsigned short f2bf(float f) {
  union { float f; unsigned int u; } v; v.f = f;
  unsigned int r = v.u + 0x7FFFu + ((v.u >> 16) & 1u);
  return (unsigned short)(r >> 16);
}

__device__ __forceinline__ void gload_lds16(const void* g, void* l) {
  __builtin_amdgcn_global_load_lds(
      (const __attribute__((address_space(1))) unsigned int*)g,
      (__attribute__((address_space(3))) unsigned int*)l, 16, 0, 0);
}

__global__ void wconv_kernel(const float* __restrict__ W, unsigned short* __restrict__ Wb) {
  int i = blockIdx.x * blockDim.x + threadIdx.x;
  if (i >= 512 * KPAD) return;
  int n = i / KPAD;
  int k = i - n * KPAD;
  float v = (k < KF) ? W[n * KF + k] : 0.0f;
  Wb[i] = f2bf(v);
}

__global__ void scatter_kernel(const float* __restrict__ m, const int* __restrict__ dst,
                               float* __restrict__ ah) {
  int i = blockIdx.x * blockDim.x + threadIdx.x;
  if (i >= NE * EF) return;
  int e = i / EF;
  int f = i - e * EF;
  atomicAdd(ah + dst[e] * EF + f, m[i]);
}

// Fused GEMM (x = [h | ah*norm], W^T) + bias + LayerNorm + ReLU.
// Tile: BM=64 rows x 512 cols, 512 threads (8 waves: 2 m-groups x 4 n-groups).
// LDS in MFMA fragment order: chunk(tile, kgroup, low16) of 16B; wave reads are
// fully linear (conflict-free) and B staging uses global_load_lds width=16.
__global__ __launch_bounds__(512) void gemm_ln_kernel(
    const float* __restrict__ h, const float* __restrict__ ah,
    const float* __restrict__ norm, const unsigned short* __restrict__ Wb,
    const float* __restrict__ bias, const float* __restrict__ gamma,
    const float* __restrict__ beta, float* __restrict__ out) {
  __shared__ __align__(16) unsigned short Alds[4 * 4 * 16 * 8];   // 4KB
  __shared__ __align__(16) unsigned short Blds[32 * 4 * 16 * 8];  // 32KB
  __shared__ float red[4][64][2];
  __shared__ float stats[64][2];

  const int t = threadIdx.x;
  const int lane = t & 63;
  const int w = t >> 6;
  const int lgrp = lane >> 4;
  const int llow = lane & 15;
  const int mg = w >> 2;  // 0..1
  const int ng = w & 3;   // 0..3
  const int blockRow = blockIdx.x * BM;

  // A staging assignment: thread -> (row am, kgroup akg, half ahalf)
  const int am = t >> 3;         // 0..63
  const int akg = (t >> 1) & 3;  // 0..3
  const int ahalf = t & 1;       // 0..1
  const int arow = blockRow + am;
  char* aldsdst = (char*)Alds + (((am >> 4) * 64 + akg * 16 + (am & 15)) * 16 + ahalf * 8);

  f32x4 acc[2][8];
#pragma unroll
  for (int i = 0; i < 2; ++i)
#pragma unroll
    for (int j = 0; j < 8; ++j) acc[i][j] = (f32x4){0.f, 0.f, 0.f, 0.f};

  for (int kt = 0; kt < 17; ++kt) {
    // ---- stage B (Wb k-slice) via global_load_lds, fragment order ----
#pragma unroll
    for (int j = 0; j < 4; ++j) {
      int nt = j * 8 + w;  // n-tile 0..31, uniform per wave
      const unsigned short* src = Wb + (nt * 16 + llow) * KPAD + kt * 32 + lgrp * 8;
      gload_lds16(src, (char*)Blds + nt * 1024);
    }
    // ---- stage A (reg-staged, f32 -> bf16) ----
    float4 av = make_float4(0.f, 0.f, 0.f, 0.f);
    if (arow < NN) {
      if (kt < 16) {
        av = *(const float4*)(h + arow * 512 + kt * 32 + akg * 8 + ahalf * 4);
      } else if (akg < 3) {  // cols 512..535 = ah*norm; 536..543 = 0
        float nv = norm[arow];
        float4 a4 = *(const float4*)(ah + arow * EF + akg * 8 + ahalf * 4);
        av = make_float4(a4.x * nv, a4.y * nv, a4.z * nv, a4.w * nv);
      }
    }
    ushort4 bv;
    bv.x = f2bf(av.x); bv.y = f2bf(av.y); bv.z = f2bf(av.z); bv.w = f2bf(av.w);
    *(ushort4*)aldsdst = bv;

    __syncthreads();

    // ---- MFMA ----
    bf16x8 af0 = *(const bf16x8*)((const char*)Alds + (((mg * 2 + 0) * 64) + lgrp * 16 + llow) * 16);
    bf16x8 af1 = *(const bf16x8*)((const char*)Alds + (((mg * 2 + 1) * 64) + lgrp * 16 + llow) * 16);
#pragma unroll
    for (int j = 0; j < 8; ++j) {
      int nt = ng * 8 + j;
      bf16x8 bf = *(const bf16x8*)((const char*)Blds + ((nt * 64) + lgrp * 16 + llow) * 16);
      acc[0][j] = __builtin_amdgcn_mfma_f32_16x16x32_bf16(af0, bf, acc[0][j], 0, 0, 0);
      acc[1][j] = __builtin_amdgcn_mfma_f32_16x16x32_bf16(af1, bf, acc[1][j], 0, 0, 0);
    }
    __syncthreads();
  }

  // ---- epilogue: bias, LN stats, normalize, relu, store ----
  float bcol[8], gcol[8], btcol[8];
#pragma unroll
  for (int j = 0; j < 8; ++j) {
    int col = (ng * 8 + j) * 16 + llow;
    bcol[j] = bias[col];
    gcol[j] = gamma[col];
    btcol[j] = beta[col];
  }
  float s[2][4], ss[2][4];
#pragma unroll
  for (int mt = 0; mt < 2; ++mt)
#pragma unroll
    for (int r = 0; r < 4; ++r) { s[mt][r] = 0.f; ss[mt][r] = 0.f; }
#pragma unroll
  for (int mt = 0; mt < 2; ++mt)
#pragma unroll
    for (int j = 0; j < 8; ++j)
#pragma unroll
      for (int r = 0; r < 4; ++r) {
        float v = acc[mt][j][r] + bcol[j];
        acc[mt][j][r] = v;
        s[mt][r] += v;
        ss[mt][r] += v * v;
      }
#pragma unroll
  for (int off = 1; off < 16; off <<= 1) {
#pragma unroll
    for (int mt = 0; mt < 2; ++mt)
#pragma unroll
      for (int r = 0; r < 4; ++r) {
        s[mt][r] += __shfl_xor(s[mt][r], off, 64);
        ss[mt][r] += __shfl_xor(ss[mt][r], off, 64);
      }
  }
  if (llow == 0) {
#pragma unroll
    for (int mt = 0; mt < 2; ++mt)
#pragma unroll
      for (int r = 0; r < 4; ++r) {
        int lrow = mg * 32 + mt * 16 + lgrp * 4 + r;
        red[ng][lrow][0] = s[mt][r];
        red[ng][lrow][1] = ss[mt][r];
      }
  }
  __syncthreads();
  if (t < 64) {
    float sum = red[0][t][0] + red[1][t][0] + red[2][t][0] + red[3][t][0];
    float sq = red[0][t][1] + red[1][t][1] + red[2][t][1] + red[3][t][1];
    float mean = sum * (1.0f / 512.0f);
    float var = sq * (1.0f / 512.0f) - mean * mean;
    stats[t][0] = mean;
    stats[t][1] = rsqrtf(var + 1e-5f);
  }
  __syncthreads();
#pragma unroll
  for (int mt = 0; mt < 2; ++mt) {
#pragma unroll
    for (int r = 0; r < 4; ++r) {
      int lrow = mg * 32 + mt * 16 + lgrp * 4 + r;
      int grow = blockRow + lrow;
      if (grow < NN) {
        float mean = stats[lrow][0];
        float rstd = stats[lrow][1];
#pragma unroll
        for (int j = 0; j < 8; ++j) {
          int col = (ng * 8 + j) * 16 + llow;
          float v = (acc[mt][j][r] - mean) * rstd * gcol[j] + btcol[j];
          out[grow * 512 + col] = fmaxf(v, 0.0f);
        }
      }
    }
  }
}

extern "C" void kernel_launch(void* const* d_in, const int* in_sizes, int n_in,
                              void* d_out, int out_size, void* d_ws, size_t ws_size,
                              hipStream_t stream) {
  const float* h = (const float*)d_in[0];
  const float* m = (const float*)d_in[1];
  const int* dst = (const int*)d_in[2];
  const float* norm = (const float*)d_in[3];
  const float* W = (const float*)d_in[4];
  const float* b = (const float*)d_in[5];
  const float* gamma = (const float*)d_in[6];
  const float* beta = (const float*)d_in[7];
  float* out = (float*)d_out;

  float* ah = (float*)d_ws;                                       // 9,600,000 B
  unsigned short* Wb = (unsigned short*)((char*)d_ws + 9600000);  // 557,056 B (16B-aligned)

  hipMemsetAsync(ah, 0, (size_t)NN * EF * sizeof(float), stream);
  wconv_kernel<<<(512 * KPAD + 255) / 256, 256, 0, stream>>>(W, Wb);
  scatter_kernel<<<(NE * EF + 255) / 256, 256, 0, stream>>>(m, dst, ah);
  gemm_ln_kernel<<<(NN + BM - 1) / BM, 512, 0, stream>>>(h, ah, norm, Wb, b, gamma, beta, out);
}